// Round 1
// 101.102 us; speedup vs baseline: 1.0163x; 1.0163x over previous
//
#include <hip/hip_runtime.h>

#define D_MODEL 128
#define SEQ 2048
#define NH 4
#define DH 32
#define NBATCH 4
#define BHN 16

typedef __attribute__((ext_vector_type(8))) short bf16x8;
typedef __attribute__((ext_vector_type(4))) float f32x4;
typedef __attribute__((ext_vector_type(4))) unsigned short u16x4;
typedef __attribute__((ext_vector_type(8))) unsigned short u16x8;

#define QSCALE (0.17677669529663687f * 1.4426950408889634f)  // log2e/sqrt(32)

static __device__ __forceinline__ unsigned short f2bf_rne(float f) {
    union { float f; unsigned int u; } v; v.f = f;
    unsigned int r = v.u + 0x7FFFu + ((v.u >> 16) & 1u);
    return (unsigned short)(r >> 16);
}

// ======================= Fragment-major layouts ==========================
// Weights wf: 32 n-tiles (q:0-7, k:8-15, v:16-23, o:24-31) x 4 kk x 64 lanes
//   x 8 elems.  B-frag: B[k=kk*32+quad*8+j][n=nt*16+col], lane=quad*16+col.
// Q  qf_ws: [bh][qi(128)][lane][8]   A-frag: Q[qi*16+col][quad*8+j]
// K  kf_ws: [bh][kbi(64)][f(2)][lane][8]  f=0: even keys kb+2*col, f=1: odd.
// V  vf_ws: [bh][kbi(64)][f(2)][lane][8]  B-frag: V[kb+quad*8+j][d], f=0:
//   d=col, f=1: d=col+16.

// ---- k0: weights -> bf16 fragment-major
__global__ __launch_bounds__(256) void k0_prep(
    const float* __restrict__ Wq, const float* __restrict__ Wk,
    const float* __restrict__ Wv, const float* __restrict__ Wo,
    unsigned short* __restrict__ wf)
{
    int tid = blockIdx.x * 256 + threadIdx.x;   // 0..8191
    int nt = tid >> 8, kk = (tid >> 6) & 3, lane = tid & 63;
    int col = lane & 15, quad = lane >> 4;
    const float* W = (nt < 8) ? Wq : (nt < 16) ? Wk : (nt < 24) ? Wv : Wo;
    int n = (nt & 7) * 16 + col;
    u16x8 v;
    #pragma unroll
    for (int j = 0; j < 8; ++j)
        v[j] = f2bf_rne(W[(kk * 32 + quad * 8 + j) * 128 + n]);
    *(u16x8*)(wf + (size_t)tid * 8) = v;
}

// ---- k1: LayerNorm -> bf16 -> MFMA QKV -> LDS repack -> WIDE frag stores.
// 256 blocks x 512 threads (8 waves), block = 32 rows = one 32-key block.
__global__ __launch_bounds__(512) void k1_ln_qkv(
    const float* __restrict__ x, const unsigned short* __restrict__ wf,
    const float* __restrict__ bq, const float* __restrict__ bk,
    const float* __restrict__ bv,
    const float* __restrict__ gamma, const float* __restrict__ beta,
    unsigned short* __restrict__ qf_ws, unsigned short* __restrict__ kf_ws,
    unsigned short* __restrict__ vf_ws)
{
    __shared__ __align__(16) unsigned short xsh[32][136];    // 8.7 KB
    __shared__ __align__(16) unsigned short stqk[32][272];   // 17.4 KB [s][n 0..255]
    __shared__ __align__(16) unsigned short stv[128][40];    // 10.2 KB [dh][s]
    const int t = threadIdx.x, w = t >> 6, lane = t & 63;
    const int row0 = blockIdx.x * 32;
    const float g0 = gamma[lane], g1 = gamma[lane + 64];
    const float be0 = beta[lane], be1 = beta[lane + 64];
    #pragma unroll
    for (int i = 0; i < 4; ++i) {
        int r = w * 4 + i;
        const float* xr = x + (size_t)(row0 + r) * 128;
        float x0 = xr[lane], x1 = xr[lane + 64];
        float s = x0 + x1, s2 = x0 * x0 + x1 * x1;
        #pragma unroll
        for (int off = 32; off > 0; off >>= 1) {
            s += __shfl_xor(s, off);
            s2 += __shfl_xor(s2, off);
        }
        float mu  = s * (1.0f / 128.0f);
        float var = s2 * (1.0f / 128.0f) - mu * mu;
        float rs  = rsqrtf(var + 1e-6f);
        xsh[r][lane]      = f2bf_rne((x0 - mu) * rs * g0 + be0);
        xsh[r][lane + 64] = f2bf_rne((x1 - mu) * rs * g1 + be1);
    }
    __syncthreads();

    const int col = lane & 15, quad = lane >> 4;
    const int mt = w & 1, mrow = mt * 16;
    const int nt0 = (w >> 1) * 6;
    bf16x8 a[4];
    #pragma unroll
    for (int kk = 0; kk < 4; ++kk)
        a[kk] = *(const bf16x8*)&xsh[mrow + col][kk * 32 + quad * 8];

    for (int nt = nt0; nt < nt0 + 6; ++nt) {
        int n = nt * 16 + col;
        const unsigned short* wrow = wf + (size_t)(nt * 4) * 512 + lane * 8;
        f32x4 c = {0.f, 0.f, 0.f, 0.f};
        #pragma unroll
        for (int kk = 0; kk < 4; ++kk) {
            bf16x8 bfr = *(const bf16x8*)(wrow + kk * 512);
            c = __builtin_amdgcn_mfma_f32_16x16x32_bf16(a[kk], bfr, c, 0, 0, 0);
        }
        int m = nt >> 3;                 // 0=q 1=k 2=v (wave-uniform)
        int nn = n & 127;
        if (m < 2) {
            float bias = (m == 0) ? bq[nn] : bk[nn];
            float scale = (m == 0) ? QSCALE : 1.0f;
            #pragma unroll
            for (int r = 0; r < 4; ++r)
                stqk[mrow + quad * 4 + r][n] = f2bf_rne((c[r] + bias) * scale);
        } else {
            float bias = bv[nn];
            u16x4 pv;
            #pragma unroll
            for (int r = 0; r < 4; ++r) pv[r] = f2bf_rne(c[r] + bias);
            *(u16x4*)&stv[nn][mrow + quad * 4] = pv;   // 8B LDS write
        }
    }
    __syncthreads();

    // ---- wide read+store phase: wave w -> (h = w>>1, par = w&1) ----
    const int b   = row0 >> 11;
    const int kbi = (row0 & (SEQ - 1)) >> 5;
    const int h   = w >> 1, par = w & 1;
    const int bh  = b * NH + h;
    {   // Q unit: qi tile = par
        u16x8 qv = *(const u16x8*)&stqk[par * 16 + col][h * 32 + quad * 8];
        int qi = ((row0 & (SEQ - 1)) >> 4) + par;
        *(u16x8*)(qf_ws + (size_t)(bh * 128 + qi) * 512 + lane * 8) = qv;
    }
    {   // K unit: f = par; lane holds K[kb + 2col+f][quad*8+j]
        u16x8 kv = *(const u16x8*)&stqk[2 * col + par][128 + h * 32 + quad * 8];
        *(u16x8*)(kf_ws + ((size_t)(bh * 64 + kbi) * 2 + par) * 512 + lane * 8) = kv;
    }
    {   // V unit: f = par; lane holds V[kb + quad*8+j][par*16+col]
        u16x8 vv = *(const u16x8*)&stv[h * 32 + par * 16 + col][quad * 8];
        *(u16x8*)(vf_ws + ((size_t)(bh * 64 + kbi) * 2 + par) * 512 + lane * 8) = vv;
    }
}

// ---- k23: attention + out-projection + residual, fused. 16 waves.
// grid (64, 4) = 256 blocks x 1024 threads. Block = 32 queries of batch b,
// ALL 4 heads. Wave w = (head = w>>2, key-quarter kh = w&3), 16 iters.
//
// R-new: SWAPPED QK^T — compute mfma(K, Q) = K·Q^T instead of Q·K^T.
// C-layout then gives lane(quad,col): S[key=kb+8*quad+2r+f][q=col], i.e.
// with the even/odd key interleave of kf_ws each lane holds exactly keys
// kb+8*quad..+7 for q=col — which IS the PV A-fragment layout. P never
// leaves registers: no p_sh (73.7 KB LDS freed), no 8 ds_write + lgkmcnt(0)
// + 2 ds_read_b128 serial round-trip per iteration, and the per-q row-sum l
// is lane-local (2 shfl_xor at the end instead of 32).
__global__ __launch_bounds__(1024) void k23_attn_out(
    const unsigned short* __restrict__ qf_ws,
    const unsigned short* __restrict__ kf_ws,
    const unsigned short* __restrict__ vf_ws,
    const unsigned short* __restrict__ wf,
    const float* __restrict__ bo, const float* __restrict__ x,
    float* __restrict__ out)
{
    __shared__ __align__(16) float comb[16][32][33];          // 67.6 KB
    __shared__ float lsh[16][32];                             // 2 KB
    __shared__ __align__(16) unsigned short ctx_sh[32][136];  // 8.7 KB

    const int w = threadIdx.x >> 6, lane = threadIdx.x & 63;
    const int col = lane & 15, quad = lane >> 4;
    const int h = w >> 2, kh = w & 3;
    const int b = blockIdx.y;
    const int bh = b * NH + h;
    const int q0 = blockIdx.x * 32;              // block's first q row
    const int qi = blockIdx.x * 2;               // 16-row q tile index

    const unsigned short* qb = qf_ws + (size_t)(bh * 128 + qi) * 512;
    const unsigned short* kb0 = kf_ws + (size_t)bh * 65536 + (size_t)(kh * 16) * 1024;
    const unsigned short* vb0 = vf_ws + (size_t)bh * 65536 + (size_t)(kh * 16) * 1024;

    bf16x8 qf0 = *(const bf16x8*)(qb + lane * 8);
    bf16x8 qf1 = *(const bf16x8*)(qb + 512 + lane * 8);

    f32x4 c00 = {0.f,0.f,0.f,0.f}, c01 = {0.f,0.f,0.f,0.f};
    f32x4 c10 = {0.f,0.f,0.f,0.f}, c11 = {0.f,0.f,0.f,0.f};
    float l0 = 0.f, l1 = 0.f;

    const unsigned short* pk = kb0;
    const unsigned short* pv = vb0;
    bf16x8 kf0 = *(const bf16x8*)(pk + lane * 8);
    bf16x8 kf1 = *(const bf16x8*)(pk + 512 + lane * 8);
    bf16x8 vf0 = *(const bf16x8*)(pv + lane * 8);
    bf16x8 vf1 = *(const bf16x8*)(pv + 512 + lane * 8);

    for (int it = 0; it < 16; ++it) {
        const unsigned short* nk = (it == 15) ? kb0 : pk + 1024;
        const unsigned short* nv = (it == 15) ? vb0 : pv + 1024;
        bf16x8 nkf0 = *(const bf16x8*)(nk + lane * 8);
        bf16x8 nkf1 = *(const bf16x8*)(nk + 512 + lane * 8);
        bf16x8 nvf0 = *(const bf16x8*)(nv + lane * 8);
        bf16x8 nvf1 = *(const bf16x8*)(nv + 512 + lane * 8);

        f32x4 z = {0.f,0.f,0.f,0.f};
        // swapped operands: A = K-frag, B = Q-frag  ->  C[key][q]
        f32x4 s00 = __builtin_amdgcn_mfma_f32_16x16x32_bf16(kf0, qf0, z, 0, 0, 0);
        f32x4 s01 = __builtin_amdgcn_mfma_f32_16x16x32_bf16(kf1, qf0, z, 0, 0, 0);
        f32x4 s10 = __builtin_amdgcn_mfma_f32_16x16x32_bf16(kf0, qf1, z, 0, 0, 0);
        f32x4 s11 = __builtin_amdgcn_mfma_f32_16x16x32_bf16(kf1, qf1, z, 0, 0, 0);

        // lane(quad,col): s00[r]=S[kb+8q'+2r][q0+col] (even), s01[r]=odd.
        // Pack in-register into the PV A-frag: elems j=2r (even), 2r+1 (odd).
        union { bf16x8 v; unsigned int u[4]; } pf0, pf1;
        #pragma unroll
        for (int r = 0; r < 4; ++r) {
            float pe = __builtin_amdgcn_exp2f(s00[r]);
            float po = __builtin_amdgcn_exp2f(s01[r]);
            l0 += pe + po;
            pf0.u[r] = (__float_as_uint(pe) >> 16) | (__float_as_uint(po) & 0xFFFF0000u);
            float qe = __builtin_amdgcn_exp2f(s10[r]);
            float qo = __builtin_amdgcn_exp2f(s11[r]);
            l1 += qe + qo;
            pf1.u[r] = (__float_as_uint(qe) >> 16) | (__float_as_uint(qo) & 0xFFFF0000u);
        }
        c00 = __builtin_amdgcn_mfma_f32_16x16x32_bf16(pf0.v, vf0, c00, 0, 0, 0);
        c01 = __builtin_amdgcn_mfma_f32_16x16x32_bf16(pf0.v, vf1, c01, 0, 0, 0);
        c10 = __builtin_amdgcn_mfma_f32_16x16x32_bf16(pf1.v, vf0, c10, 0, 0, 0);
        c11 = __builtin_amdgcn_mfma_f32_16x16x32_bf16(pf1.v, vf1, c11, 0, 0, 0);
        kf0 = nkf0; kf1 = nkf1; vf0 = nvf0; vf1 = nvf1;
        pk = nk; pv = nv;
    }

    // l0/l1 hold partial row-sums for q=col (tile0/tile1) over this lane's
    // key subset {8*quad..8*quad+7} x 16 iters; reduce across the 4 quads.
    l0 += __shfl_xor(l0, 16); l0 += __shfl_xor(l0, 32);
    l1 += __shfl_xor(l1, 16); l1 += __shfl_xor(l1, 32);

    #pragma unroll
    for (int r = 0; r < 4; ++r) {
        int rr = quad * 4 + r;
        comb[w][rr][col]           = c00[r];
        comb[w][rr][16 + col]      = c01[r];
        comb[w][16 + rr][col]      = c10[r];
        comb[w][16 + rr][16 + col] = c11[r];
    }
    if (quad == 0) {
        lsh[w][col]      = l0;
        lsh[w][16 + col] = l1;
    }
    __syncthreads();

    // combine 4 key-quarters, normalize, store bf16 ctx_sh[32 rows][128 d]
    {
        int row = threadIdx.x >> 5;          // 0..31
        int dg  = (threadIdx.x & 31) * 4;    // 4-col group
        int hh  = dg >> 5;                   // head of this col group
        int wb  = hh * 4;
        float linv = 1.0f / (lsh[wb][row] + lsh[wb + 1][row]
                           + lsh[wb + 2][row] + lsh[wb + 3][row]);
        int dl = dg & 31;
        u16x4 ov;
        #pragma unroll
        for (int j = 0; j < 4; ++j)
            ov[j] = f2bf_rne((comb[wb][row][dl + j] + comb[wb + 1][row][dl + j]
                            + comb[wb + 2][row][dl + j] + comb[wb + 3][row][dl + j])
                             * linv);
        *(u16x4*)&ctx_sh[row][dg] = ov;
    }
    __syncthreads();

    // out-projection: 16 waves <-> 16 (n-tile, m-tile) units
    {
        int nt = w & 7, mt = w >> 3;
        bf16x8 a[4];
        #pragma unroll
        for (int kk = 0; kk < 4; ++kk)
            a[kk] = *(const bf16x8*)&ctx_sh[mt * 16 + col][kk * 32 + quad * 8];
        int n = nt * 16 + col;
        int nt_g = 24 + nt;
        f32x4 c = {0.f, 0.f, 0.f, 0.f};
        #pragma unroll
        for (int kk = 0; kk < 4; ++kk) {
            bf16x8 bfr = *(const bf16x8*)(wf + ((size_t)(nt_g * 4 + kk) * 64 + lane) * 8);
            c = __builtin_amdgcn_mfma_f32_16x16x32_bf16(a[kk], bfr, c, 0, 0, 0);
        }
        float bias = bo[n];
        #pragma unroll
        for (int r = 0; r < 4; ++r) {
            size_t row_g = (size_t)b * SEQ + q0 + mt * 16 + quad * 4 + r;
            out[row_g * 128 + n] = c[r] + bias + x[row_g * 128 + n];
        }
    }
}

extern "C" void kernel_launch(void* const* d_in, const int* in_sizes, int n_in,
                              void* d_out, int out_size, void* d_ws, size_t ws_size,
                              hipStream_t stream) {
    const float* x     = (const float*)d_in[0];
    const float* Wq    = (const float*)d_in[1];
    const float* bq    = (const float*)d_in[2];
    const float* Wk    = (const float*)d_in[3];
    const float* bk    = (const float*)d_in[4];
    const float* Wv    = (const float*)d_in[5];
    const float* bv    = (const float*)d_in[6];
    const float* gamma = (const float*)d_in[7];
    const float* beta  = (const float*)d_in[8];
    const float* Wo    = (const float*)d_in[9];
    const float* bo    = (const float*)d_in[10];
    float* out = (float*)d_out;

    const size_t QKV_ELEMS = (size_t)BHN * SEQ * DH;  // 1M
    unsigned short* qf_ws = (unsigned short*)d_ws;
    unsigned short* kf_ws = qf_ws + QKV_ELEMS;
    unsigned short* vf_ws = kf_ws + QKV_ELEMS;
    unsigned short* wf    = vf_ws + QKV_ELEMS;        // 512*128 bf16 frag-major

    k0_prep<<<32, 256, 0, stream>>>(Wq, Wk, Wv, Wo, wf);
    k1_ln_qkv<<<256, 512, 0, stream>>>(x, wf, bq, bk, bv, gamma, beta,
                                       qf_ws, kf_ws, vf_ws);
    k23_attn_out<<<dim3(64, 4), 1024, 0, stream>>>(qf_ws, kf_ws, vf_ws, wf,
                                                   bo, x, out);
}

// Round 2
// 99.872 us; speedup vs baseline: 1.0288x; 1.0123x over previous
//
#include <hip/hip_runtime.h>

#define D_MODEL 128
#define SEQ 2048
#define NH 4
#define DH 32
#define NBATCH 4
#define BHN 16

typedef __attribute__((ext_vector_type(8))) short bf16x8;
typedef __attribute__((ext_vector_type(4))) float f32x4;
typedef __attribute__((ext_vector_type(4))) unsigned short u16x4;
typedef __attribute__((ext_vector_type(8))) unsigned short u16x8;

#define QSCALE (0.17677669529663687f * 1.4426950408889634f)  // log2e/sqrt(32)

static __device__ __forceinline__ unsigned short f2bf_rne(float f) {
    union { float f; unsigned int u; } v; v.f = f;
    unsigned int r = v.u + 0x7FFFu + ((v.u >> 16) & 1u);
    return (unsigned short)(r >> 16);
}

// ======================= Fragment-major layouts ==========================
// Weight unit u = nt*4+kk: [u][lane][8] bf16, B-frag:
//   B[k=kk*32+quad*8+j][n=nt*16+col], lane=quad*16+col.
// Q  qf_ws: [bh][qi(128)][lane][8]   A-frag: Q[qi*16+col][quad*8+j]
// K  kf_ws: [bh][kbi(64)][f(2)][lane][8]  f=0: even keys kb+2*col, f=1: odd.
// V  vf_ws: [bh][kbi(64)][f(2)][lane][8]  B-frag: V[kb+quad*8+j][d], f=0:
//   d=col, f=1: d=col+16.
//
// R2: k0 eliminated. k1 converts QKV weights into LDS (wsh, same unit
// layout) during its prologue, hidden under the LN phase; k23 converts Wo
// into LDS (wo_sh) at block start. Saves one dispatch + k0's low-occupancy
// duration (~2-3 us). Also: s_setprio(1) around k23's MFMA clusters (T5).

// ---- k1: LayerNorm -> bf16 -> MFMA QKV -> LDS repack -> WIDE frag stores.
// 256 blocks x 512 threads (8 waves), block = 32 rows = one 32-key block.
__global__ __launch_bounds__(512) void k1_ln_qkv(
    const float* __restrict__ x,
    const float* __restrict__ Wq, const float* __restrict__ Wk,
    const float* __restrict__ Wv,
    const float* __restrict__ bq, const float* __restrict__ bk,
    const float* __restrict__ bv,
    const float* __restrict__ gamma, const float* __restrict__ beta,
    unsigned short* __restrict__ qf_ws, unsigned short* __restrict__ kf_ws,
    unsigned short* __restrict__ vf_ws)
{
    __shared__ __align__(16) unsigned short wsh[96 * 512];   // 96 KB QKV frags
    __shared__ __align__(16) unsigned short xsh[32][136];    // 8.7 KB
    __shared__ __align__(16) unsigned short stqk[32][272];   // 17.4 KB [s][n 0..255]
    __shared__ __align__(16) unsigned short stv[128][40];    // 10.2 KB [dh][s]
    const int t = threadIdx.x, w = t >> 6, lane = t & 63;
    const int col = lane & 15, quad = lane >> 4;
    const int row0 = blockIdx.x * 32;
    const float g0 = gamma[lane], g1 = gamma[lane + 64];
    const float be0 = beta[lane], be1 = beta[lane + 64];
    #pragma unroll
    for (int i = 0; i < 4; ++i) {
        int r = w * 4 + i;
        const float* xr = x + (size_t)(row0 + r) * 128;
        float x0 = xr[lane], x1 = xr[lane + 64];
        float s = x0 + x1, s2 = x0 * x0 + x1 * x1;
        #pragma unroll
        for (int off = 32; off > 0; off >>= 1) {
            s += __shfl_xor(s, off);
            s2 += __shfl_xor(s2, off);
        }
        float mu  = s * (1.0f / 128.0f);
        float var = s2 * (1.0f / 128.0f) - mu * mu;
        float rs  = rsqrtf(var + 1e-6f);
        xsh[r][lane]      = f2bf_rne((x0 - mu) * rs * g0 + be0);
        xsh[r][lane + 64] = f2bf_rne((x1 - mu) * rs * g1 + be1);
    }

    // --- weight conversion: 8 waves x 12 units = 96 units (24 nt x 4 kk).
    // Same layout as old k0: wsh[u*512 + lane*8 + j].
    #pragma unroll
    for (int i = 0; i < 12; ++i) {
        int u = w * 12 + i;
        int nt = u >> 2, kk = u & 3;
        const float* W = (nt < 8) ? Wq : (nt < 16) ? Wk : Wv;
        int n = (nt & 7) * 16 + col;
        u16x8 v;
        #pragma unroll
        for (int j = 0; j < 8; ++j)
            v[j] = f2bf_rne(W[(kk * 32 + quad * 8 + j) * 128 + n]);
        *(u16x8*)&wsh[(size_t)u * 512 + lane * 8] = v;
    }
    __syncthreads();

    const int mt = w & 1, mrow = mt * 16;
    const int nt0 = (w >> 1) * 6;
    bf16x8 a[4];
    #pragma unroll
    for (int kk = 0; kk < 4; ++kk)
        a[kk] = *(const bf16x8*)&xsh[mrow + col][kk * 32 + quad * 8];

    for (int nt = nt0; nt < nt0 + 6; ++nt) {
        int n = nt * 16 + col;
        f32x4 c = {0.f, 0.f, 0.f, 0.f};
        #pragma unroll
        for (int kk = 0; kk < 4; ++kk) {
            bf16x8 bfr = *(const bf16x8*)&wsh[(size_t)(nt * 4 + kk) * 512 + lane * 8];
            c = __builtin_amdgcn_mfma_f32_16x16x32_bf16(a[kk], bfr, c, 0, 0, 0);
        }
        int m = nt >> 3;                 // 0=q 1=k 2=v (wave-uniform)
        int nn = n & 127;
        if (m < 2) {
            float bias = (m == 0) ? bq[nn] : bk[nn];
            float scale = (m == 0) ? QSCALE : 1.0f;
            #pragma unroll
            for (int r = 0; r < 4; ++r)
                stqk[mrow + quad * 4 + r][n] = f2bf_rne((c[r] + bias) * scale);
        } else {
            float bias = bv[nn];
            u16x4 pv;
            #pragma unroll
            for (int r = 0; r < 4; ++r) pv[r] = f2bf_rne(c[r] + bias);
            *(u16x4*)&stv[nn][mrow + quad * 4] = pv;   // 8B LDS write
        }
    }
    __syncthreads();

    // ---- wide read+store phase: wave w -> (h = w>>1, par = w&1) ----
    const int b   = row0 >> 11;
    const int kbi = (row0 & (SEQ - 1)) >> 5;
    const int h   = w >> 1, par = w & 1;
    const int bh  = b * NH + h;
    {   // Q unit: qi tile = par
        u16x8 qv = *(const u16x8*)&stqk[par * 16 + col][h * 32 + quad * 8];
        int qi = ((row0 & (SEQ - 1)) >> 4) + par;
        *(u16x8*)(qf_ws + (size_t)(bh * 128 + qi) * 512 + lane * 8) = qv;
    }
    {   // K unit: f = par; lane holds K[kb + 2col+f][quad*8+j]
        u16x8 kv = *(const u16x8*)&stqk[2 * col + par][128 + h * 32 + quad * 8];
        *(u16x8*)(kf_ws + ((size_t)(bh * 64 + kbi) * 2 + par) * 512 + lane * 8) = kv;
    }
    {   // V unit: f = par; lane holds V[kb + quad*8+j][par*16+col]
        u16x8 vv = *(const u16x8*)&stv[h * 32 + par * 16 + col][quad * 8];
        *(u16x8*)(vf_ws + ((size_t)(bh * 64 + kbi) * 2 + par) * 512 + lane * 8) = vv;
    }
}

// ---- k23: attention + out-projection + residual, fused. 16 waves.
// grid (64, 4) = 256 blocks x 1024 threads. Block = 32 queries of batch b,
// ALL 4 heads. Wave w = (head = w>>2, key-quarter kh = w&3), 16 iters.
// Swapped QK^T (mfma(K,Q)): P stays in registers (see R1 notes).
__global__ __launch_bounds__(1024) void k23_attn_out(
    const unsigned short* __restrict__ qf_ws,
    const unsigned short* __restrict__ kf_ws,
    const unsigned short* __restrict__ vf_ws,
    const float* __restrict__ Wo,
    const float* __restrict__ bo, const float* __restrict__ x,
    float* __restrict__ out)
{
    __shared__ __align__(16) unsigned short wo_sh[32 * 512]; // 32 KB Wo frags
    __shared__ __align__(16) float comb[16][32][33];         // 67.6 KB
    __shared__ float lsh[16][32];                            // 2 KB
    __shared__ __align__(16) unsigned short ctx_sh[32][136]; // 8.7 KB

    const int w = threadIdx.x >> 6, lane = threadIdx.x & 63;
    const int col = lane & 15, quad = lane >> 4;
    const int h = w >> 2, kh = w & 3;
    const int b = blockIdx.y;
    const int bh = b * NH + h;
    const int q0 = blockIdx.x * 32;              // block's first q row
    const int qi = blockIdx.x * 2;               // 16-row q tile index

    // --- Wo -> LDS frags: 16 waves x 2 units = 32 units (8 nt x 4 kk).
    // Layout identical to old wf region 24..31: wo_sh[(nt*4+kk)*512+lane*8+j].
    #pragma unroll
    for (int i = 0; i < 2; ++i) {
        int u = w * 2 + i;                       // 0..31
        int nt = u >> 2, kk = u & 3;
        int n = nt * 16 + col;
        u16x8 vv;
        #pragma unroll
        for (int j = 0; j < 8; ++j)
            vv[j] = f2bf_rne(Wo[(kk * 32 + quad * 8 + j) * 128 + n]);
        *(u16x8*)&wo_sh[(size_t)u * 512 + lane * 8] = vv;
    }

    const unsigned short* qb = qf_ws + (size_t)(bh * 128 + qi) * 512;
    const unsigned short* kb0 = kf_ws + (size_t)bh * 65536 + (size_t)(kh * 16) * 1024;
    const unsigned short* vb0 = vf_ws + (size_t)bh * 65536 + (size_t)(kh * 16) * 1024;

    bf16x8 qf0 = *(const bf16x8*)(qb + lane * 8);
    bf16x8 qf1 = *(const bf16x8*)(qb + 512 + lane * 8);

    f32x4 c00 = {0.f,0.f,0.f,0.f}, c01 = {0.f,0.f,0.f,0.f};
    f32x4 c10 = {0.f,0.f,0.f,0.f}, c11 = {0.f,0.f,0.f,0.f};
    float l0 = 0.f, l1 = 0.f;

    const unsigned short* pk = kb0;
    const unsigned short* pv = vb0;
    bf16x8 kf0 = *(const bf16x8*)(pk + lane * 8);
    bf16x8 kf1 = *(const bf16x8*)(pk + 512 + lane * 8);
    bf16x8 vf0 = *(const bf16x8*)(pv + lane * 8);
    bf16x8 vf1 = *(const bf16x8*)(pv + 512 + lane * 8);

    for (int it = 0; it < 16; ++it) {
        const unsigned short* nk = (it == 15) ? kb0 : pk + 1024;
        const unsigned short* nv = (it == 15) ? vb0 : pv + 1024;
        bf16x8 nkf0 = *(const bf16x8*)(nk + lane * 8);
        bf16x8 nkf1 = *(const bf16x8*)(nk + 512 + lane * 8);
        bf16x8 nvf0 = *(const bf16x8*)(nv + lane * 8);
        bf16x8 nvf1 = *(const bf16x8*)(nv + 512 + lane * 8);

        f32x4 z = {0.f,0.f,0.f,0.f};
        // swapped operands: A = K-frag, B = Q-frag  ->  C[key][q]
        __builtin_amdgcn_s_setprio(1);
        f32x4 s00 = __builtin_amdgcn_mfma_f32_16x16x32_bf16(kf0, qf0, z, 0, 0, 0);
        f32x4 s01 = __builtin_amdgcn_mfma_f32_16x16x32_bf16(kf1, qf0, z, 0, 0, 0);
        f32x4 s10 = __builtin_amdgcn_mfma_f32_16x16x32_bf16(kf0, qf1, z, 0, 0, 0);
        f32x4 s11 = __builtin_amdgcn_mfma_f32_16x16x32_bf16(kf1, qf1, z, 0, 0, 0);
        __builtin_amdgcn_s_setprio(0);

        // lane(quad,col): s00[r]=S[kb+8q'+2r][q0+col] (even), s01[r]=odd.
        // Pack in-register into the PV A-frag: elems j=2r (even), 2r+1 (odd).
        union { bf16x8 v; unsigned int u[4]; } pf0, pf1;
        #pragma unroll
        for (int r = 0; r < 4; ++r) {
            float pe = __builtin_amdgcn_exp2f(s00[r]);
            float po = __builtin_amdgcn_exp2f(s01[r]);
            l0 += pe + po;
            pf0.u[r] = (__float_as_uint(pe) >> 16) | (__float_as_uint(po) & 0xFFFF0000u);
            float qe = __builtin_amdgcn_exp2f(s10[r]);
            float qo = __builtin_amdgcn_exp2f(s11[r]);
            l1 += qe + qo;
            pf1.u[r] = (__float_as_uint(qe) >> 16) | (__float_as_uint(qo) & 0xFFFF0000u);
        }
        __builtin_amdgcn_s_setprio(1);
        c00 = __builtin_amdgcn_mfma_f32_16x16x32_bf16(pf0.v, vf0, c00, 0, 0, 0);
        c01 = __builtin_amdgcn_mfma_f32_16x16x32_bf16(pf0.v, vf1, c01, 0, 0, 0);
        c10 = __builtin_amdgcn_mfma_f32_16x16x32_bf16(pf1.v, vf0, c10, 0, 0, 0);
        c11 = __builtin_amdgcn_mfma_f32_16x16x32_bf16(pf1.v, vf1, c11, 0, 0, 0);
        __builtin_amdgcn_s_setprio(0);
        kf0 = nkf0; kf1 = nkf1; vf0 = nvf0; vf1 = nvf1;
        pk = nk; pv = nv;
    }

    // l0/l1 hold partial row-sums for q=col (tile0/tile1) over this lane's
    // key subset {8*quad..8*quad+7} x 16 iters; reduce across the 4 quads.
    l0 += __shfl_xor(l0, 16); l0 += __shfl_xor(l0, 32);
    l1 += __shfl_xor(l1, 16); l1 += __shfl_xor(l1, 32);

    #pragma unroll
    for (int r = 0; r < 4; ++r) {
        int rr = quad * 4 + r;
        comb[w][rr][col]           = c00[r];
        comb[w][rr][16 + col]      = c01[r];
        comb[w][16 + rr][col]      = c10[r];
        comb[w][16 + rr][16 + col] = c11[r];
    }
    if (quad == 0) {
        lsh[w][col]      = l0;
        lsh[w][16 + col] = l1;
    }
    __syncthreads();

    // combine 4 key-quarters, normalize, store bf16 ctx_sh[32 rows][128 d]
    {
        int row = threadIdx.x >> 5;          // 0..31
        int dg  = (threadIdx.x & 31) * 4;    // 4-col group
        int hh  = dg >> 5;                   // head of this col group
        int wb  = hh * 4;
        float linv = 1.0f / (lsh[wb][row] + lsh[wb + 1][row]
                           + lsh[wb + 2][row] + lsh[wb + 3][row]);
        int dl = dg & 31;
        u16x4 ov;
        #pragma unroll
        for (int j = 0; j < 4; ++j)
            ov[j] = f2bf_rne((comb[wb][row][dl + j] + comb[wb + 1][row][dl + j]
                            + comb[wb + 2][row][dl + j] + comb[wb + 3][row][dl + j])
                             * linv);
        *(u16x4*)&ctx_sh[row][dg] = ov;
    }
    __syncthreads();

    // out-projection: 16 waves <-> 16 (n-tile, m-tile) units
    {
        int nt = w & 7, mt = w >> 3;
        bf16x8 a[4];
        #pragma unroll
        for (int kk = 0; kk < 4; ++kk)
            a[kk] = *(const bf16x8*)&ctx_sh[mt * 16 + col][kk * 32 + quad * 8];
        int n = nt * 16 + col;
        f32x4 c = {0.f, 0.f, 0.f, 0.f};
        #pragma unroll
        for (int kk = 0; kk < 4; ++kk) {
            bf16x8 bfr = *(const bf16x8*)&wo_sh[(size_t)(nt * 4 + kk) * 512 + lane * 8];
            c = __builtin_amdgcn_mfma_f32_16x16x32_bf16(a[kk], bfr, c, 0, 0, 0);
        }
        float bias = bo[n];
        #pragma unroll
        for (int r = 0; r < 4; ++r) {
            size_t row_g = (size_t)b * SEQ + q0 + mt * 16 + quad * 4 + r;
            out[row_g * 128 + n] = c[r] + bias + x[row_g * 128 + n];
        }
    }
}

extern "C" void kernel_launch(void* const* d_in, const int* in_sizes, int n_in,
                              void* d_out, int out_size, void* d_ws, size_t ws_size,
                              hipStream_t stream) {
    const float* x     = (const float*)d_in[0];
    const float* Wq    = (const float*)d_in[1];
    const float* bq    = (const float*)d_in[2];
    const float* Wk    = (const float*)d_in[3];
    const float* bk    = (const float*)d_in[4];
    const float* Wv    = (const float*)d_in[5];
    const float* bv    = (const float*)d_in[6];
    const float* gamma = (const float*)d_in[7];
    const float* beta  = (const float*)d_in[8];
    const float* Wo    = (const float*)d_in[9];
    const float* bo    = (const float*)d_in[10];
    float* out = (float*)d_out;

    const size_t QKV_ELEMS = (size_t)BHN * SEQ * DH;  // 1M
    unsigned short* qf_ws = (unsigned short*)d_ws;
    unsigned short* kf_ws = qf_ws + QKV_ELEMS;
    unsigned short* vf_ws = kf_ws + QKV_ELEMS;

    k1_ln_qkv<<<256, 512, 0, stream>>>(x, Wq, Wk, Wv, bq, bk, bv, gamma, beta,
                                       qf_ws, kf_ws, vf_ws);
    k23_attn_out<<<dim3(64, 4), 1024, 0, stream>>>(qf_ws, kf_ws, vf_ws, Wo,
                                                   bo, x, out);
}